// Round 7
// baseline (643.314 us; speedup 1.0000x reference)
//
#include <hip/hip_runtime.h>

#define FIN 128
#define FHID 32
#define FOUT 64
#define MAXDEG 10

// edge_index arrives as int32 (harness converts integer inputs to int):
// layout [2, E] flat: src = ei[e], dst = ei[E + e].

__device__ __forceinline__ float bf2f(unsigned short u) {
    union { unsigned int i; float f; } c; c.i = ((unsigned int)u) << 16; return c.f;
}
__device__ __forceinline__ unsigned short f2bf(float f) {
    union { float f; unsigned int i; } c; c.f = f;
    unsigned int r = c.i + 0x7FFF + ((c.i >> 16) & 1);   // round-nearest-even
    return (unsigned short)(r >> 16);
}
__device__ __forceinline__ float bflo(unsigned int w) { return bf2f((unsigned short)(w & 0xffff)); }
__device__ __forceinline__ float bfhi(unsigned int w) { return bf2f((unsigned short)(w >> 16)); }

// ---------- CSR build ----------

__global__ __launch_bounds__(256) void k_count(const int* __restrict__ ei, int E, int N,
                                               int* __restrict__ deg) {
    int e = blockIdx.x * 256 + threadIdx.x;
    if (e >= E) return;
    int d = ei[E + e];
    if ((unsigned)d < (unsigned)N) atomicAdd(deg + d, 1);
}

__global__ __launch_bounds__(256) void k_blocksum(const int* __restrict__ deg, int N,
                                                  int* __restrict__ partial) {
    __shared__ int tmp[256];
    int t = threadIdx.x;
    int i = blockIdx.x * 256 + t;
    tmp[t] = (i < N) ? deg[i] : 0;
    __syncthreads();
    for (int off = 128; off > 0; off >>= 1) {
        if (t < off) tmp[t] += tmp[t + off];
        __syncthreads();
    }
    if (t == 0) partial[blockIdx.x] = tmp[0];
}

// single-block exclusive scan of partial[0..NB) -> offsets   (requires NB <= 1024)
__global__ __launch_bounds__(1024) void k_scanpartial(const int* __restrict__ partial, int NB,
                                                      int* __restrict__ offsets) {
    __shared__ int tmp[1024];
    int t = threadIdx.x;
    int v = (t < NB) ? partial[t] : 0;
    tmp[t] = v;
    __syncthreads();
    for (int off = 1; off < 1024; off <<= 1) {
        int a = (t >= off) ? tmp[t - off] : 0;
        __syncthreads();
        tmp[t] += a;
        __syncthreads();
    }
    if (t < NB) offsets[t] = tmp[t] - v;
}

__global__ __launch_bounds__(256) void k_scandeg(const int* __restrict__ deg, int N,
                                                 const int* __restrict__ offsets,
                                                 int* __restrict__ cursor) {
    __shared__ int tmp[256];
    int t = threadIdx.x;
    int i = blockIdx.x * 256 + t;
    int v = (i < N) ? deg[i] : 0;
    tmp[t] = v;
    __syncthreads();
    for (int off = 1; off < 256; off <<= 1) {
        int a = (t >= off) ? tmp[t - off] : 0;
        __syncthreads();
        tmp[t] += a;
        __syncthreads();
    }
    if (i < N) cursor[i] = offsets[blockIdx.x] + tmp[t] - v;
}

// adj written via atomicExch: atomics resolve at the device coherence point and
// avoid the cross-XCD line-ownership ping-pong that a plain scattered store causes
// (R6 measured 105 MB HBM WRITE_SIZE for a 6.4 MB array = 16x amplification).
__global__ __launch_bounds__(256) void k_fill(const int* __restrict__ ei, int E, int N,
                                              int* __restrict__ cursor, int* __restrict__ adj) {
    int e = blockIdx.x * 256 + threadIdx.x;
    if (e >= E) return;
    int s = ei[e];
    int d = ei[E + e];
    if ((unsigned)s >= (unsigned)N || (unsigned)d >= (unsigned)N) return;
    int pos = atomicAdd(cursor + d, 1);   // cursor ends at row end = rowstart + deg
    if ((unsigned)pos < (unsigned)E) atomicExch(adj + pos, s);
}

// ---------- pre1: z10 = x@W1[10] (bf16), r1 = x@Wr1[10]+b1[10] (bf16) ----------
// 16 nodes per wave, register-blocked: lanes 0-31 own z columns, lanes 32-63 own
// r columns; ONE weight load feeds 16 FMAs (R6's version re-read weights per node
// -> 96 VMEM/node). deg<10 nodes get r1 patched by k_fix1.
__global__ __launch_bounds__(256) void k_pre1(const float* __restrict__ x,
                                              const float* __restrict__ W1,
                                              const float* __restrict__ b1,
                                              const float* __restrict__ Wr1,
                                              unsigned short* __restrict__ z10,
                                              unsigned short* __restrict__ r1, int N) {
    int wave = (int)(((long long)blockIdx.x * 256 + threadIdx.x) >> 6);
    int q = wave * 16;
    if (q >= N) return;
    int lane = threadIdx.x & 63;
    int u = lane >> 5;
    int o = lane & 31;
    const float* Wbase = (u == 0 ? W1 : Wr1) + (size_t)MAXDEG * (FIN * FHID) + o;
    const float4* xrow[16];
#pragma unroll
    for (int t = 0; t < 16; ++t) {
        int cn = q + t; if (cn > N - 1) cn = N - 1;
        xrow[t] = (const float4*)(x + (size_t)cn * FIN);
    }
    float acc[16];
#pragma unroll
    for (int t = 0; t < 16; ++t) acc[t] = 0.f;
    for (int c = 0; c < FIN / 4; ++c) {
        float w0 = Wbase[(c * 4 + 0) * FHID];
        float w1 = Wbase[(c * 4 + 1) * FHID];
        float w2 = Wbase[(c * 4 + 2) * FHID];
        float w3 = Wbase[(c * 4 + 3) * FHID];
#pragma unroll
        for (int h = 0; h < 2; ++h) {
            float4 xs[8];
#pragma unroll
            for (int t = 0; t < 8; ++t) xs[t] = xrow[h * 8 + t][c];
#pragma unroll
            for (int t = 0; t < 8; ++t) {
                acc[h * 8 + t] += xs[t].x * w0 + xs[t].y * w1
                                + xs[t].z * w2 + xs[t].w * w3;
            }
        }
    }
    float bv = (u == 1) ? b1[MAXDEG * FHID + o] : 0.f;
#pragma unroll
    for (int t = 0; t < 16; ++t) {
        int n = q + t;
        if (n < N) {
            if (u == 0) z10[(size_t)n * FHID + o] = f2bf(acc[t]);
            else        r1[(size_t)n * FHID + o]  = f2bf(acc[t] + bv);
        }
    }
}

// fixup: recompute r1 with the node's true bucket for the ~4% deg<10 nodes.
__global__ __launch_bounds__(256) void k_fix1(const float* __restrict__ x,
                                              const int* __restrict__ deg,
                                              const float* __restrict__ b1,
                                              const float* __restrict__ Wr1,
                                              unsigned short* __restrict__ r1, int N) {
    int wavebase = blockIdx.x * 256 + (threadIdx.x & 192);
    int lane = threadIdx.x & 63;
    int nl = wavebase + lane;
    bool fl = (nl < N) && (deg[nl] < MAXDEG);
    unsigned long long mask = __ballot(fl);
    int u = lane >> 5, o = lane & 31;
    while (mask) {
        int b = __ffsll(mask) - 1;
        mask &= mask - 1;
        int n = wavebase + b;
        int d = deg[n];
        const float* Wr = Wr1 + (size_t)d * (FIN * FHID) + o;
        const float4* xr = (const float4*)(x + (size_t)n * FIN);
        float acc = 0.f;
        for (int c = u * 16; c < u * 16 + 16; ++c) {   // split-K across halves
            float4 xv = xr[c];
            acc += xv.x * Wr[(c * 4 + 0) * FHID] + xv.y * Wr[(c * 4 + 1) * FHID]
                 + xv.z * Wr[(c * 4 + 2) * FHID] + xv.w * Wr[(c * 4 + 3) * FHID];
        }
        acc += __shfl_xor(acc, 32);
        if (lane < 32) r1[(size_t)n * FHID + o] = f2bf(acc + b1[d * FHID + o]);
    }
}

// ---------- layer1: deg>=10 fast path gathers bf16 z10 rows with high MLP ----------
__global__ __launch_bounds__(256) void k_layer1b(const float* __restrict__ x,
                                                 const unsigned short* __restrict__ z10,
                                                 const unsigned short* __restrict__ r1,
                                                 const int* __restrict__ deg,
                                                 const int* __restrict__ cursor,
                                                 const int* __restrict__ adj,
                                                 const float* __restrict__ W1,
                                                 unsigned short* __restrict__ out1, int N) {
    int wave = (int)(((long long)blockIdx.x * 256 + threadIdx.x) >> 6);
    if (wave >= N) return;
    int n = wave;
    int lane = threadIdx.x & 63;
    int dg = deg[n];
    int e1 = cursor[n];
    int e0 = e1 - dg;
    if (dg >= MAXDEG) {
        int g = lane >> 3, l = lane & 7;
        int myk = e0 + lane;
        int sidx = (myk < e1) ? adj[myk] : 0;
        int cnt = min(dg, 64);
        float a0 = 0.f, a1 = 0.f, a2 = 0.f, a3 = 0.f;
        for (int i = 0; i * 8 < cnt; ++i) {
            int idx = i * 8 + g;
            int s = __shfl(sidx, idx);
            if (idx < cnt) {
                ushort4 uv = *(const ushort4*)(z10 + (size_t)s * FHID + l * 4);
                a0 += bf2f(uv.x); a1 += bf2f(uv.y); a2 += bf2f(uv.z); a3 += bf2f(uv.w);
            }
        }
        for (int k = e0 + 64 + g; k < e1; k += 8) {  // deg>64: essentially never
            int s = adj[k];
            ushort4 uv = *(const ushort4*)(z10 + (size_t)s * FHID + l * 4);
            a0 += bf2f(uv.x); a1 += bf2f(uv.y); a2 += bf2f(uv.z); a3 += bf2f(uv.w);
        }
#pragma unroll
        for (int m = 8; m <= 32; m <<= 1) {
            a0 += __shfl_xor(a0, m); a1 += __shfl_xor(a1, m);
            a2 += __shfl_xor(a2, m); a3 += __shfl_xor(a3, m);
        }
        if (lane < 8) {
            ushort4 rv = *(const ushort4*)(r1 + (size_t)n * FHID + l * 4);
            ushort4 w;
            w.x = f2bf(fmaxf(a0 + bf2f(rv.x), 0.f));
            w.y = f2bf(fmaxf(a1 + bf2f(rv.y), 0.f));
            w.z = f2bf(fmaxf(a2 + bf2f(rv.z), 0.f));
            w.w = f2bf(fmaxf(a3 + bf2f(rv.w), 0.f));
            *(ushort4*)(out1 + (size_t)n * FHID + l * 4) = w;
        }
    } else {
        // rare (~4% of nodes): gather raw fp32 x rows, matvec with this node's bucket
        float2 hs = make_float2(0.f, 0.f);
        for (int k = e0; k < e1; ++k) {
            int s = adj[k];
            float2 v = *(const float2*)(x + (size_t)s * FIN + lane * 2);
            hs.x += v.x; hs.y += v.y;
        }
        int o = lane & 31;
        const float* Wp = W1 + (size_t)dg * (FIN * FHID) + o;
        float acc = 0.f;
#pragma unroll
        for (int f = 0; f < FIN; ++f) {
            float hv = __shfl((f & 1) ? hs.y : hs.x, f >> 1);
            acc += hv * Wp[f * FHID];
        }
        if (lane < 32) {
            float rv = bf2f(r1[(size_t)n * FHID + o]);
            out1[(size_t)n * FHID + o] = f2bf(fmaxf(acc + rv, 0.f));
        }
    }
}

// ---------- pre2: p = y@W2[10] (bf16), r2 = y@Wr2[10]+b2[10] (bf16) ----------
// 8 nodes per wave, register-blocked; each lane owns one of 64 output columns
// for both p and r2. deg<10 nodes get r2 patched by k_fix2.
__global__ __launch_bounds__(256) void k_pre2(const unsigned short* __restrict__ y,
                                              const float* __restrict__ W2,
                                              const float* __restrict__ b2,
                                              const float* __restrict__ Wr2,
                                              unsigned short* __restrict__ p,
                                              unsigned short* __restrict__ r2, int N) {
    int wave = (int)(((long long)blockIdx.x * 256 + threadIdx.x) >> 6);
    int q = wave * 8;
    if (q >= N) return;
    int j = threadIdx.x & 63;
    const float* Wp = W2  + (size_t)MAXDEG * (FHID * FOUT) + j;
    const float* Wr = Wr2 + (size_t)MAXDEG * (FHID * FOUT) + j;
    const uint4* yrow[8];
#pragma unroll
    for (int t = 0; t < 8; ++t) {
        int cn = q + t; if (cn > N - 1) cn = N - 1;
        yrow[t] = (const uint4*)(y + (size_t)cn * FHID);
    }
    float ap[8], ar[8];
#pragma unroll
    for (int t = 0; t < 8; ++t) { ap[t] = 0.f; ar[t] = 0.f; }
#pragma unroll
    for (int c = 0; c < 4; ++c) {
        uint4 ys[8];
#pragma unroll
        for (int t = 0; t < 8; ++t) ys[t] = yrow[t][c];
#pragma unroll
        for (int m = 0; m < 8; ++m) {
            int f = c * 8 + m;
            float wp = Wp[f * FOUT];
            float wr = Wr[f * FOUT];
#pragma unroll
            for (int t = 0; t < 8; ++t) {
                unsigned int word = (m >> 1 == 0) ? ys[t].x : (m >> 1 == 1) ? ys[t].y
                                   : (m >> 1 == 2) ? ys[t].z : ys[t].w;
                float v = (m & 1) ? bfhi(word) : bflo(word);
                ap[t] += v * wp;
                ar[t] += v * wr;
            }
        }
    }
    float bv = b2[MAXDEG * FOUT + j];
#pragma unroll
    for (int t = 0; t < 8; ++t) {
        int n = q + t;
        if (n < N) {
            p[(size_t)n * FOUT + j]  = f2bf(ap[t]);
            r2[(size_t)n * FOUT + j] = f2bf(ar[t] + bv);
        }
    }
}

// fixup: recompute r2 with the node's true bucket for deg<10 nodes.
__global__ __launch_bounds__(256) void k_fix2(const unsigned short* __restrict__ y,
                                              const int* __restrict__ deg,
                                              const float* __restrict__ b2,
                                              const float* __restrict__ Wr2,
                                              unsigned short* __restrict__ r2, int N) {
    int wavebase = blockIdx.x * 256 + (threadIdx.x & 192);
    int lane = threadIdx.x & 63;
    int nl = wavebase + lane;
    bool fl = (nl < N) && (deg[nl] < MAXDEG);
    unsigned long long mask = __ballot(fl);
    while (mask) {
        int b = __ffsll(mask) - 1;
        mask &= mask - 1;
        int n = wavebase + b;
        int d = deg[n];
        const float* Wr = Wr2 + (size_t)d * (FHID * FOUT) + lane;
        const uint4* yr = (const uint4*)(y + (size_t)n * FHID);
        float acc = b2[d * FOUT + lane];
        for (int c = 0; c < 4; ++c) {
            uint4 yv = yr[c];
            acc += bflo(yv.x) * Wr[(c * 8 + 0) * FOUT] + bfhi(yv.x) * Wr[(c * 8 + 1) * FOUT]
                 + bflo(yv.y) * Wr[(c * 8 + 2) * FOUT] + bfhi(yv.y) * Wr[(c * 8 + 3) * FOUT]
                 + bflo(yv.z) * Wr[(c * 8 + 4) * FOUT] + bfhi(yv.z) * Wr[(c * 8 + 5) * FOUT]
                 + bflo(yv.w) * Wr[(c * 8 + 6) * FOUT] + bfhi(yv.w) * Wr[(c * 8 + 7) * FOUT];
        }
        r2[(size_t)n * FOUT + lane] = f2bf(acc);
    }
}

// ---------- layer2: deg>=10 fast path gathers bf16 p rows (128B) with high MLP ----------
__global__ __launch_bounds__(256) void k_layer2b(const unsigned short* __restrict__ p,
                                                 const unsigned short* __restrict__ r2,
                                                 const unsigned short* __restrict__ y,
                                                 const int* __restrict__ deg,
                                                 const int* __restrict__ cursor,
                                                 const int* __restrict__ adj,
                                                 const float* __restrict__ W2,
                                                 float* __restrict__ out, int N) {
    int wave = (int)(((long long)blockIdx.x * 256 + threadIdx.x) >> 6);
    if (wave >= N) return;
    int n = wave;
    int lane = threadIdx.x & 63;
    int dg = deg[n];
    int e1 = cursor[n];
    int e0 = e1 - dg;
    if (dg >= MAXDEG) {
        int g = lane >> 3, l = lane & 7;
        int myk = e0 + lane;
        int sidx = (myk < e1) ? adj[myk] : 0;
        int cnt = min(dg, 64);
        float a[8];
#pragma unroll
        for (int m = 0; m < 8; ++m) a[m] = 0.f;
        for (int i = 0; i * 8 < cnt; ++i) {
            int idx = i * 8 + g;
            int s = __shfl(sidx, idx);
            if (idx < cnt) {
                uint4 uv = *(const uint4*)(p + (size_t)s * FOUT + l * 8);
                a[0] += bflo(uv.x); a[1] += bfhi(uv.x);
                a[2] += bflo(uv.y); a[3] += bfhi(uv.y);
                a[4] += bflo(uv.z); a[5] += bfhi(uv.z);
                a[6] += bflo(uv.w); a[7] += bfhi(uv.w);
            }
        }
        for (int k = e0 + 64 + g; k < e1; k += 8) {  // deg>64: essentially never
            int s = adj[k];
            uint4 uv = *(const uint4*)(p + (size_t)s * FOUT + l * 8);
            a[0] += bflo(uv.x); a[1] += bfhi(uv.x);
            a[2] += bflo(uv.y); a[3] += bfhi(uv.y);
            a[4] += bflo(uv.z); a[5] += bfhi(uv.z);
            a[6] += bflo(uv.w); a[7] += bfhi(uv.w);
        }
#pragma unroll
        for (int m = 8; m <= 32; m <<= 1) {
#pragma unroll
            for (int t = 0; t < 8; ++t) a[t] += __shfl_xor(a[t], m);
        }
        if (lane < 8) {
            uint4 rv = *(const uint4*)(r2 + (size_t)n * FOUT + l * 8);
            float4 o0, o1;
            o0.x = a[0] + bflo(rv.x); o0.y = a[1] + bfhi(rv.x);
            o0.z = a[2] + bflo(rv.y); o0.w = a[3] + bfhi(rv.y);
            o1.x = a[4] + bflo(rv.z); o1.y = a[5] + bfhi(rv.z);
            o1.z = a[6] + bflo(rv.w); o1.w = a[7] + bfhi(rv.w);
            float* op = out + (size_t)n * FOUT + l * 8;
            *(float4*)op = o0;
            *(float4*)(op + 4) = o1;
        }
    } else {
        // rare: gather bf16 y rows (4-way ILP), then 32->64 matvec; r2 has root+bias
        int g = lane >> 4, l = lane & 15;
        float2 h = make_float2(0.f, 0.f);
        for (int k = e0 + g; k < e1; k += 4) {
            int s = adj[k];
            ushort2 uv = *(const ushort2*)(y + (size_t)s * FHID + l * 2);
            h.x += bf2f(uv.x); h.y += bf2f(uv.y);
        }
        h.x += __shfl_xor(h.x, 16); h.y += __shfl_xor(h.y, 16);
        h.x += __shfl_xor(h.x, 32); h.y += __shfl_xor(h.y, 32);
        const float* Wp = W2 + (size_t)dg * (FHID * FOUT) + lane;
        float acc = bf2f(r2[(size_t)n * FOUT + lane]);
#pragma unroll
        for (int f = 0; f < FHID; ++f) {
            float hf = __shfl((f & 1) ? h.y : h.x, f >> 1);
            acc += hf * Wp[f * FOUT];
        }
        out[(size_t)n * FOUT + lane] = acc;
    }
}

extern "C" void kernel_launch(void* const* d_in, const int* in_sizes, int n_in,
                              void* d_out, int out_size, void* d_ws, size_t ws_size,
                              hipStream_t stream) {
    const float* x   = (const float*)d_in[0];
    const int*   ei  = (const int*)d_in[1];   // int32, [2, E] flat
    const float* W1  = (const float*)d_in[2];
    const float* b1  = (const float*)d_in[3];
    const float* Wr1 = (const float*)d_in[4];
    const float* W2  = (const float*)d_in[5];
    const float* b2  = (const float*)d_in[6];
    const float* Wr2 = (const float*)d_in[7];

    int N = in_sizes[0] / FIN;
    int E = in_sizes[1] / 2;
    int NB = (N + 255) / 256;

    char* ws = (char*)d_ws;
    size_t off = 0;
    auto alloc = [&](size_t bytes) {
        void* ptr = ws + off;
        off += (bytes + 511) / 512 * 512;
        return ptr;
    };
    int* deg              = (int*)alloc((size_t)N * sizeof(int));
    int* cursor           = (int*)alloc((size_t)N * sizeof(int));
    int* partial          = (int*)alloc((size_t)NB * sizeof(int));
    int* offsets          = (int*)alloc((size_t)NB * sizeof(int));
    int* adj              = (int*)alloc((size_t)E * sizeof(int));
    unsigned short* z10   = (unsigned short*)alloc((size_t)N * FHID * 2);
    unsigned short* r1    = (unsigned short*)alloc((size_t)N * FHID * 2);
    unsigned short* out1  = (unsigned short*)alloc((size_t)N * FHID * 2);
    unsigned short* p     = (unsigned short*)alloc((size_t)N * FOUT * 2);
    unsigned short* r2    = (unsigned short*)alloc((size_t)N * FOUT * 2);
    // total ~52 MB for N=100K, E=1.6M

    float* out = (float*)d_out;

    hipMemsetAsync(deg, 0, (size_t)N * sizeof(int), stream);

    int eb = (E + 255) / 256;
    k_count<<<eb, 256, 0, stream>>>(ei, E, N, deg);
    k_blocksum<<<NB, 256, 0, stream>>>(deg, N, partial);
    k_scanpartial<<<1, 1024, 0, stream>>>(partial, NB, offsets);
    k_scandeg<<<NB, 256, 0, stream>>>(deg, N, offsets, cursor);
    k_fill<<<eb, 256, 0, stream>>>(ei, E, N, cursor, adj);

    int nb16 = (N + 63) / 64;     // pre1: wave per 16 nodes
    int nb8  = (N + 31) / 32;     // pre2: wave per 8 nodes
    int nbfx = (N + 255) / 256;   // fixups: wave scans 64 nodes
    int nb_node = (N + 3) / 4;    // layer kernels: wave per node

    k_pre1<<<nb16, 256, 0, stream>>>(x, W1, b1, Wr1, z10, r1, N);
    k_fix1<<<nbfx, 256, 0, stream>>>(x, deg, b1, Wr1, r1, N);
    k_layer1b<<<nb_node, 256, 0, stream>>>(x, z10, r1, deg, cursor, adj, W1, out1, N);
    k_pre2<<<nb8, 256, 0, stream>>>(out1, W2, b2, Wr2, p, r2, N);
    k_fix2<<<nbfx, 256, 0, stream>>>(out1, deg, b2, Wr2, r2, N);
    k_layer2b<<<nb_node, 256, 0, stream>>>(p, r2, out1, deg, cursor, adj, W2, out, N);
}

// Round 8
// 531.211 us; speedup vs baseline: 1.2110x; 1.2110x over previous
//
#include <hip/hip_runtime.h>

#define FIN 128
#define FHID 32
#define FOUT 64
#define MAXDEG 10
#define BSH 8              // dst bucket = dst >> 8 (256 dsts per bucket)
#define ACHUNK 4096        // edges per pass-A workgroup (16 per thread)

// edge_index arrives as int32 (harness converts integer inputs to int):
// layout [2, E] flat: src = ei[e], dst = ei[E + e].

__device__ __forceinline__ float bf2f(unsigned short u) {
    union { unsigned int i; float f; } c; c.i = ((unsigned int)u) << 16; return c.f;
}
__device__ __forceinline__ unsigned short f2bf(float f) {
    union { float f; unsigned int i; } c; c.f = f;
    unsigned int r = c.i + 0x7FFF + ((c.i >> 16) & 1);   // round-nearest-even
    return (unsigned short)(r >> 16);
}
__device__ __forceinline__ float bflo(unsigned int w) { return bf2f((unsigned short)(w & 0xffff)); }
__device__ __forceinline__ float bfhi(unsigned int w) { return bf2f((unsigned short)(w >> 16)); }

// ---------- CSR build ----------

__global__ __launch_bounds__(256) void k_count(const int* __restrict__ ei, int E, int N,
                                               int* __restrict__ deg) {
    int e = blockIdx.x * 256 + threadIdx.x;
    if (e >= E) return;
    int d = ei[E + e];
    if ((unsigned)d < (unsigned)N) atomicAdd(deg + d, 1);
}

__global__ __launch_bounds__(256) void k_blocksum(const int* __restrict__ deg, int N,
                                                  int* __restrict__ partial) {
    __shared__ int tmp[256];
    int t = threadIdx.x;
    int i = blockIdx.x * 256 + t;
    tmp[t] = (i < N) ? deg[i] : 0;
    __syncthreads();
    for (int off = 128; off > 0; off >>= 1) {
        if (t < off) tmp[t] += tmp[t + off];
        __syncthreads();
    }
    if (t == 0) partial[blockIdx.x] = tmp[0];
}

// single-block exclusive scan of partial[0..NB) -> offsets   (requires NB <= 1024)
__global__ __launch_bounds__(1024) void k_scanpartial(const int* __restrict__ partial, int NB,
                                                      int* __restrict__ offsets) {
    __shared__ int tmp[1024];
    int t = threadIdx.x;
    int v = (t < NB) ? partial[t] : 0;
    tmp[t] = v;
    __syncthreads();
    for (int off = 1; off < 1024; off <<= 1) {
        int a = (t >= off) ? tmp[t - off] : 0;
        __syncthreads();
        tmp[t] += a;
        __syncthreads();
    }
    if (t < NB) offsets[t] = tmp[t] - v;
}

__global__ __launch_bounds__(256) void k_scandeg(const int* __restrict__ deg, int N,
                                                 const int* __restrict__ offsets,
                                                 int* __restrict__ cursor) {
    __shared__ int tmp[256];
    int t = threadIdx.x;
    int i = blockIdx.x * 256 + t;
    int v = (i < N) ? deg[i] : 0;
    tmp[t] = v;
    __syncthreads();
    for (int off = 1; off < 256; off <<= 1) {
        int a = (t >= off) ? tmp[t - off] : 0;
        __syncthreads();
        tmp[t] += a;
        __syncthreads();
    }
    if (i < N) cursor[i] = offsets[blockIdx.x] + tmp[t] - v;
}

// gcur[b] = adj start offset of bucket b (= row start of first dst in bucket)
__global__ __launch_bounds__(256) void k_initb(const int* __restrict__ cursor,
                                               int* __restrict__ gcur, int K) {
    int b = blockIdx.x * 256 + threadIdx.x;
    if (b < K) gcur[b] = cursor[b << BSH];
}

// Pass A: bucket edges by dst>>8 into pairs[], line-coalesced appends.
// (R7 measured: direct 4B scatter into adj costs 100 MB HBM writeback — each
// 64B line is written by ~16 edges from random XCDs. Bucketing makes every
// pairs/adj line owned by one workgroup so L2 merges the writes.)
__global__ __launch_bounds__(256) void k_passA(const int* __restrict__ ei, int E, int N,
                                               int* __restrict__ gcur,
                                               int2* __restrict__ pairs) {
    __shared__ int hist[1024];
    __shared__ int base[1024];
    int K = ((N + 255) >> BSH);
    int t = threadIdx.x;
    long long cb = (long long)blockIdx.x * ACHUNK;
    for (int i = t; i < K; i += 256) hist[i] = 0;
    __syncthreads();
    int sv[16], dv[16];
#pragma unroll
    for (int i = 0; i < 16; ++i) {
        sv[i] = -1; dv[i] = 0;
        long long e = cb + t + (long long)i * 256;
        if (e < E) {
            int ss = ei[e];
            int dd = ei[E + e];
            if ((unsigned)ss < (unsigned)N && (unsigned)dd < (unsigned)N) {
                sv[i] = ss; dv[i] = dd;
            }
        }
    }
#pragma unroll
    for (int i = 0; i < 16; ++i)
        if (sv[i] >= 0) atomicAdd(&hist[dv[i] >> BSH], 1);
    __syncthreads();
    for (int i = t; i < K; i += 256) {
        int h = hist[i];
        base[i] = h ? atomicAdd(&gcur[i], h) : 0;
    }
    __syncthreads();
    for (int i = t; i < K; i += 256) hist[i] = 0;
    __syncthreads();
#pragma unroll
    for (int i = 0; i < 16; ++i) {
        if (sv[i] >= 0) {
            int b = dv[i] >> BSH;
            int off = atomicAdd(&hist[b], 1);
            pairs[base[b] + off] = make_int2(sv[i], dv[i]);
        }
    }
}

// Pass B: one workgroup per bucket; private LDS cursors; adj region (~16KB)
// written only by this workgroup -> full-line writebacks. Flushes row ends
// back into cursor[] (layer kernels read cursor[n] as row END).
__global__ __launch_bounds__(256) void k_passB(const int2* __restrict__ pairs,
                                               const int* __restrict__ gcur,
                                               int* __restrict__ cursor,
                                               int* __restrict__ adj, int N) {
    __shared__ int cur[256];
    int b = blockIdx.x;
    int lo = b << BSH;
    int hi = min(lo + 256, N);
    int t = threadIdx.x;
    int cnt = hi - lo;
    if (t < cnt) cur[t] = cursor[lo + t];
    int pstart = cursor[lo];     // row start of first dst (unmutated: range is private)
    int pend = gcur[b];          // bucket end after pass A
    __syncthreads();
    for (int i = pstart + t; i < pend; i += 256) {
        int2 pr = pairs[i];
        int pos = atomicAdd(&cur[pr.y - lo], 1);
        adj[pos] = pr.x;
    }
    __syncthreads();
    if (t < cnt) cursor[lo + t] = cur[t];
}

// ---------- pre1: z10 = x@W1[10] (bf16), r1 = x@Wr1[10]+b1[10] (bf16) ----------
// 16 nodes per wave, register-blocked: lanes 0-31 own z columns, lanes 32-63 own
// r columns; ONE weight load feeds 16 FMAs. deg<10 nodes patched by k_fix1.
__global__ __launch_bounds__(256) void k_pre1(const float* __restrict__ x,
                                              const float* __restrict__ W1,
                                              const float* __restrict__ b1,
                                              const float* __restrict__ Wr1,
                                              unsigned short* __restrict__ z10,
                                              unsigned short* __restrict__ r1, int N) {
    int wave = (int)(((long long)blockIdx.x * 256 + threadIdx.x) >> 6);
    int q = wave * 16;
    if (q >= N) return;
    int lane = threadIdx.x & 63;
    int u = lane >> 5;
    int o = lane & 31;
    const float* Wbase = (u == 0 ? W1 : Wr1) + (size_t)MAXDEG * (FIN * FHID) + o;
    const float4* xrow[16];
#pragma unroll
    for (int t = 0; t < 16; ++t) {
        int cn = q + t; if (cn > N - 1) cn = N - 1;
        xrow[t] = (const float4*)(x + (size_t)cn * FIN);
    }
    float acc[16];
#pragma unroll
    for (int t = 0; t < 16; ++t) acc[t] = 0.f;
    for (int c = 0; c < FIN / 4; ++c) {
        float w0 = Wbase[(c * 4 + 0) * FHID];
        float w1 = Wbase[(c * 4 + 1) * FHID];
        float w2 = Wbase[(c * 4 + 2) * FHID];
        float w3 = Wbase[(c * 4 + 3) * FHID];
#pragma unroll
        for (int h = 0; h < 2; ++h) {
            float4 xs[8];
#pragma unroll
            for (int t = 0; t < 8; ++t) xs[t] = xrow[h * 8 + t][c];
#pragma unroll
            for (int t = 0; t < 8; ++t) {
                acc[h * 8 + t] += xs[t].x * w0 + xs[t].y * w1
                                + xs[t].z * w2 + xs[t].w * w3;
            }
        }
    }
    float bv = (u == 1) ? b1[MAXDEG * FHID + o] : 0.f;
#pragma unroll
    for (int t = 0; t < 16; ++t) {
        int n = q + t;
        if (n < N) {
            if (u == 0) z10[(size_t)n * FHID + o] = f2bf(acc[t]);
            else        r1[(size_t)n * FHID + o]  = f2bf(acc[t] + bv);
        }
    }
}

// fixup: recompute r1 with the node's true bucket for the ~4% deg<10 nodes.
__global__ __launch_bounds__(256) void k_fix1(const float* __restrict__ x,
                                              const int* __restrict__ deg,
                                              const float* __restrict__ b1,
                                              const float* __restrict__ Wr1,
                                              unsigned short* __restrict__ r1, int N) {
    int wavebase = blockIdx.x * 256 + (threadIdx.x & 192);
    int lane = threadIdx.x & 63;
    int nl = wavebase + lane;
    bool fl = (nl < N) && (deg[nl] < MAXDEG);
    unsigned long long mask = __ballot(fl);
    int u = lane >> 5, o = lane & 31;
    while (mask) {
        int b = __ffsll(mask) - 1;
        mask &= mask - 1;
        int n = wavebase + b;
        int d = deg[n];
        const float* Wr = Wr1 + (size_t)d * (FIN * FHID) + o;
        const float4* xr = (const float4*)(x + (size_t)n * FIN);
        float acc = 0.f;
        for (int c = u * 16; c < u * 16 + 16; ++c) {   // split-K across halves
            float4 xv = xr[c];
            acc += xv.x * Wr[(c * 4 + 0) * FHID] + xv.y * Wr[(c * 4 + 1) * FHID]
                 + xv.z * Wr[(c * 4 + 2) * FHID] + xv.w * Wr[(c * 4 + 3) * FHID];
        }
        acc += __shfl_xor(acc, 32);
        if (lane < 32) r1[(size_t)n * FHID + o] = f2bf(acc + b1[d * FHID + o]);
    }
}

// ---------- layer1: deg>=10 fast path gathers bf16 z10 rows with high MLP ----------
__global__ __launch_bounds__(256) void k_layer1b(const float* __restrict__ x,
                                                 const unsigned short* __restrict__ z10,
                                                 const unsigned short* __restrict__ r1,
                                                 const int* __restrict__ deg,
                                                 const int* __restrict__ cursor,
                                                 const int* __restrict__ adj,
                                                 const float* __restrict__ W1,
                                                 unsigned short* __restrict__ out1, int N) {
    int wave = (int)(((long long)blockIdx.x * 256 + threadIdx.x) >> 6);
    if (wave >= N) return;
    int n = wave;
    int lane = threadIdx.x & 63;
    int dg = deg[n];
    int e1 = cursor[n];
    int e0 = e1 - dg;
    if (dg >= MAXDEG) {
        int g = lane >> 3, l = lane & 7;
        int myk = e0 + lane;
        int sidx = (myk < e1) ? adj[myk] : 0;
        int cnt = min(dg, 64);
        float a0 = 0.f, a1 = 0.f, a2 = 0.f, a3 = 0.f;
        for (int i = 0; i * 8 < cnt; ++i) {
            int idx = i * 8 + g;
            int s = __shfl(sidx, idx);
            if (idx < cnt) {
                ushort4 uv = *(const ushort4*)(z10 + (size_t)s * FHID + l * 4);
                a0 += bf2f(uv.x); a1 += bf2f(uv.y); a2 += bf2f(uv.z); a3 += bf2f(uv.w);
            }
        }
        for (int k = e0 + 64 + g; k < e1; k += 8) {  // deg>64: essentially never
            int s = adj[k];
            ushort4 uv = *(const ushort4*)(z10 + (size_t)s * FHID + l * 4);
            a0 += bf2f(uv.x); a1 += bf2f(uv.y); a2 += bf2f(uv.z); a3 += bf2f(uv.w);
        }
#pragma unroll
        for (int m = 8; m <= 32; m <<= 1) {
            a0 += __shfl_xor(a0, m); a1 += __shfl_xor(a1, m);
            a2 += __shfl_xor(a2, m); a3 += __shfl_xor(a3, m);
        }
        if (lane < 8) {
            ushort4 rv = *(const ushort4*)(r1 + (size_t)n * FHID + l * 4);
            ushort4 w;
            w.x = f2bf(fmaxf(a0 + bf2f(rv.x), 0.f));
            w.y = f2bf(fmaxf(a1 + bf2f(rv.y), 0.f));
            w.z = f2bf(fmaxf(a2 + bf2f(rv.z), 0.f));
            w.w = f2bf(fmaxf(a3 + bf2f(rv.w), 0.f));
            *(ushort4*)(out1 + (size_t)n * FHID + l * 4) = w;
        }
    } else {
        // rare (~4% of nodes): gather raw fp32 x rows, matvec with this node's bucket
        float2 hs = make_float2(0.f, 0.f);
        for (int k = e0; k < e1; ++k) {
            int s = adj[k];
            float2 v = *(const float2*)(x + (size_t)s * FIN + lane * 2);
            hs.x += v.x; hs.y += v.y;
        }
        int o = lane & 31;
        const float* Wp = W1 + (size_t)dg * (FIN * FHID) + o;
        float acc = 0.f;
#pragma unroll
        for (int f = 0; f < FIN; ++f) {
            float hv = __shfl((f & 1) ? hs.y : hs.x, f >> 1);
            acc += hv * Wp[f * FHID];
        }
        if (lane < 32) {
            float rv = bf2f(r1[(size_t)n * FHID + o]);
            out1[(size_t)n * FHID + o] = f2bf(fmaxf(acc + rv, 0.f));
        }
    }
}

// ---------- pre2: p = y@W2[10] (bf16), r2 = y@Wr2[10]+b2[10] (bf16) ----------
__global__ __launch_bounds__(256) void k_pre2(const unsigned short* __restrict__ y,
                                              const float* __restrict__ W2,
                                              const float* __restrict__ b2,
                                              const float* __restrict__ Wr2,
                                              unsigned short* __restrict__ p,
                                              unsigned short* __restrict__ r2, int N) {
    int wave = (int)(((long long)blockIdx.x * 256 + threadIdx.x) >> 6);
    int q = wave * 8;
    if (q >= N) return;
    int j = threadIdx.x & 63;
    const float* Wp = W2  + (size_t)MAXDEG * (FHID * FOUT) + j;
    const float* Wr = Wr2 + (size_t)MAXDEG * (FHID * FOUT) + j;
    const uint4* yrow[8];
#pragma unroll
    for (int t = 0; t < 8; ++t) {
        int cn = q + t; if (cn > N - 1) cn = N - 1;
        yrow[t] = (const uint4*)(y + (size_t)cn * FHID);
    }
    float ap[8], ar[8];
#pragma unroll
    for (int t = 0; t < 8; ++t) { ap[t] = 0.f; ar[t] = 0.f; }
#pragma unroll
    for (int c = 0; c < 4; ++c) {
        uint4 ys[8];
#pragma unroll
        for (int t = 0; t < 8; ++t) ys[t] = yrow[t][c];
#pragma unroll
        for (int m = 0; m < 8; ++m) {
            int f = c * 8 + m;
            float wp = Wp[f * FOUT];
            float wr = Wr[f * FOUT];
#pragma unroll
            for (int t = 0; t < 8; ++t) {
                unsigned int word = (m >> 1 == 0) ? ys[t].x : (m >> 1 == 1) ? ys[t].y
                                   : (m >> 1 == 2) ? ys[t].z : ys[t].w;
                float v = (m & 1) ? bfhi(word) : bflo(word);
                ap[t] += v * wp;
                ar[t] += v * wr;
            }
        }
    }
    float bv = b2[MAXDEG * FOUT + j];
#pragma unroll
    for (int t = 0; t < 8; ++t) {
        int n = q + t;
        if (n < N) {
            p[(size_t)n * FOUT + j]  = f2bf(ap[t]);
            r2[(size_t)n * FOUT + j] = f2bf(ar[t] + bv);
        }
    }
}

// fixup: recompute r2 with the node's true bucket for deg<10 nodes.
__global__ __launch_bounds__(256) void k_fix2(const unsigned short* __restrict__ y,
                                              const int* __restrict__ deg,
                                              const float* __restrict__ b2,
                                              const float* __restrict__ Wr2,
                                              unsigned short* __restrict__ r2, int N) {
    int wavebase = blockIdx.x * 256 + (threadIdx.x & 192);
    int lane = threadIdx.x & 63;
    int nl = wavebase + lane;
    bool fl = (nl < N) && (deg[nl] < MAXDEG);
    unsigned long long mask = __ballot(fl);
    while (mask) {
        int b = __ffsll(mask) - 1;
        mask &= mask - 1;
        int n = wavebase + b;
        int d = deg[n];
        const float* Wr = Wr2 + (size_t)d * (FHID * FOUT) + lane;
        const uint4* yr = (const uint4*)(y + (size_t)n * FHID);
        float acc = b2[d * FOUT + lane];
        for (int c = 0; c < 4; ++c) {
            uint4 yv = yr[c];
            acc += bflo(yv.x) * Wr[(c * 8 + 0) * FOUT] + bfhi(yv.x) * Wr[(c * 8 + 1) * FOUT]
                 + bflo(yv.y) * Wr[(c * 8 + 2) * FOUT] + bfhi(yv.y) * Wr[(c * 8 + 3) * FOUT]
                 + bflo(yv.z) * Wr[(c * 8 + 4) * FOUT] + bfhi(yv.z) * Wr[(c * 8 + 5) * FOUT]
                 + bflo(yv.w) * Wr[(c * 8 + 6) * FOUT] + bfhi(yv.w) * Wr[(c * 8 + 7) * FOUT];
        }
        r2[(size_t)n * FOUT + lane] = f2bf(acc);
    }
}

// ---------- layer2: deg>=10 fast path gathers bf16 p rows (128B) with high MLP ----------
__global__ __launch_bounds__(256) void k_layer2b(const unsigned short* __restrict__ p,
                                                 const unsigned short* __restrict__ r2,
                                                 const unsigned short* __restrict__ y,
                                                 const int* __restrict__ deg,
                                                 const int* __restrict__ cursor,
                                                 const int* __restrict__ adj,
                                                 const float* __restrict__ W2,
                                                 float* __restrict__ out, int N) {
    int wave = (int)(((long long)blockIdx.x * 256 + threadIdx.x) >> 6);
    if (wave >= N) return;
    int n = wave;
    int lane = threadIdx.x & 63;
    int dg = deg[n];
    int e1 = cursor[n];
    int e0 = e1 - dg;
    if (dg >= MAXDEG) {
        int g = lane >> 3, l = lane & 7;
        int myk = e0 + lane;
        int sidx = (myk < e1) ? adj[myk] : 0;
        int cnt = min(dg, 64);
        float a[8];
#pragma unroll
        for (int m = 0; m < 8; ++m) a[m] = 0.f;
        for (int i = 0; i * 8 < cnt; ++i) {
            int idx = i * 8 + g;
            int s = __shfl(sidx, idx);
            if (idx < cnt) {
                uint4 uv = *(const uint4*)(p + (size_t)s * FOUT + l * 8);
                a[0] += bflo(uv.x); a[1] += bfhi(uv.x);
                a[2] += bflo(uv.y); a[3] += bfhi(uv.y);
                a[4] += bflo(uv.z); a[5] += bfhi(uv.z);
                a[6] += bflo(uv.w); a[7] += bfhi(uv.w);
            }
        }
        for (int k = e0 + 64 + g; k < e1; k += 8) {  // deg>64: essentially never
            int s = adj[k];
            uint4 uv = *(const uint4*)(p + (size_t)s * FOUT + l * 8);
            a[0] += bflo(uv.x); a[1] += bfhi(uv.x);
            a[2] += bflo(uv.y); a[3] += bfhi(uv.y);
            a[4] += bflo(uv.z); a[5] += bfhi(uv.z);
            a[6] += bflo(uv.w); a[7] += bfhi(uv.w);
        }
#pragma unroll
        for (int m = 8; m <= 32; m <<= 1) {
#pragma unroll
            for (int t = 0; t < 8; ++t) a[t] += __shfl_xor(a[t], m);
        }
        if (lane < 8) {
            uint4 rv = *(const uint4*)(r2 + (size_t)n * FOUT + l * 8);
            float4 o0, o1;
            o0.x = a[0] + bflo(rv.x); o0.y = a[1] + bfhi(rv.x);
            o0.z = a[2] + bflo(rv.y); o0.w = a[3] + bfhi(rv.y);
            o1.x = a[4] + bflo(rv.z); o1.y = a[5] + bfhi(rv.z);
            o1.z = a[6] + bflo(rv.w); o1.w = a[7] + bfhi(rv.w);
            float* op = out + (size_t)n * FOUT + l * 8;
            *(float4*)op = o0;
            *(float4*)(op + 4) = o1;
        }
    } else {
        // rare: gather bf16 y rows (4-way ILP), then 32->64 matvec; r2 has root+bias
        int g = lane >> 4, l = lane & 15;
        float2 h = make_float2(0.f, 0.f);
        for (int k = e0 + g; k < e1; k += 4) {
            int s = adj[k];
            ushort2 uv = *(const ushort2*)(y + (size_t)s * FHID + l * 2);
            h.x += bf2f(uv.x); h.y += bf2f(uv.y);
        }
        h.x += __shfl_xor(h.x, 16); h.y += __shfl_xor(h.y, 16);
        h.x += __shfl_xor(h.x, 32); h.y += __shfl_xor(h.y, 32);
        const float* Wp = W2 + (size_t)dg * (FHID * FOUT) + lane;
        float acc = bf2f(r2[(size_t)n * FOUT + lane]);
#pragma unroll
        for (int f = 0; f < FHID; ++f) {
            float hf = __shfl((f & 1) ? h.y : h.x, f >> 1);
            acc += hf * Wp[f * FOUT];
        }
        out[(size_t)n * FOUT + lane] = acc;
    }
}

extern "C" void kernel_launch(void* const* d_in, const int* in_sizes, int n_in,
                              void* d_out, int out_size, void* d_ws, size_t ws_size,
                              hipStream_t stream) {
    const float* x   = (const float*)d_in[0];
    const int*   ei  = (const int*)d_in[1];   // int32, [2, E] flat
    const float* W1  = (const float*)d_in[2];
    const float* b1  = (const float*)d_in[3];
    const float* Wr1 = (const float*)d_in[4];
    const float* W2  = (const float*)d_in[5];
    const float* b2  = (const float*)d_in[6];
    const float* Wr2 = (const float*)d_in[7];

    int N = in_sizes[0] / FIN;
    int E = in_sizes[1] / 2;
    int NB = (N + 255) / 256;
    int K  = (N + 255) >> BSH;   // dst buckets (== NB for BSH=8)

    char* ws = (char*)d_ws;
    size_t off = 0;
    auto alloc = [&](size_t bytes) {
        void* ptr = ws + off;
        off += (bytes + 511) / 512 * 512;
        return ptr;
    };
    int* deg              = (int*)alloc((size_t)N * sizeof(int));
    int* cursor           = (int*)alloc((size_t)N * sizeof(int));
    int* partial          = (int*)alloc((size_t)NB * sizeof(int));
    int* offsets          = (int*)alloc((size_t)NB * sizeof(int));
    int* gcur             = (int*)alloc((size_t)K * sizeof(int));
    int* adj              = (int*)alloc((size_t)E * sizeof(int));
    unsigned short* z10   = (unsigned short*)alloc((size_t)N * FHID * 2);
    unsigned short* r1    = (unsigned short*)alloc((size_t)N * FHID * 2);
    unsigned short* out1  = (unsigned short*)alloc((size_t)N * FHID * 2);
    unsigned short* p     = (unsigned short*)alloc((size_t)N * FOUT * 2);
    unsigned short* r2    = (unsigned short*)alloc((size_t)N * FOUT * 2);
    // pairs (E*8B = 12.8MB) aliases p (N*FOUT*2 = 12.8MB): dead until k_pre2 runs.
    int2* pairs = (int2*)p;
    // total ~52 MB for N=100K, E=1.6M

    float* out = (float*)d_out;

    hipMemsetAsync(deg, 0, (size_t)N * sizeof(int), stream);

    int eb = (E + 255) / 256;
    k_count<<<eb, 256, 0, stream>>>(ei, E, N, deg);
    k_blocksum<<<NB, 256, 0, stream>>>(deg, N, partial);
    k_scanpartial<<<1, 1024, 0, stream>>>(partial, NB, offsets);
    k_scandeg<<<NB, 256, 0, stream>>>(deg, N, offsets, cursor);
    k_initb<<<(K + 255) / 256, 256, 0, stream>>>(cursor, gcur, K);
    int nwgA = (E + ACHUNK - 1) / ACHUNK;
    k_passA<<<nwgA, 256, 0, stream>>>(ei, E, N, gcur, pairs);
    k_passB<<<K, 256, 0, stream>>>(pairs, gcur, cursor, adj, N);

    int nb16 = (N + 63) / 64;     // pre1: wave per 16 nodes
    int nb8  = (N + 31) / 32;     // pre2: wave per 8 nodes
    int nbfx = (N + 255) / 256;   // fixups: wave scans 64 nodes
    int nb_node = (N + 3) / 4;    // layer kernels: wave per node

    k_pre1<<<nb16, 256, 0, stream>>>(x, W1, b1, Wr1, z10, r1, N);
    k_fix1<<<nbfx, 256, 0, stream>>>(x, deg, b1, Wr1, r1, N);
    k_layer1b<<<nb_node, 256, 0, stream>>>(x, z10, r1, deg, cursor, adj, W1, out1, N);
    k_pre2<<<nb8, 256, 0, stream>>>(out1, W2, b2, Wr2, p, r2, N);
    k_fix2<<<nbfx, 256, 0, stream>>>(out1, deg, b2, Wr2, r2, N);
    k_layer2b<<<nb_node, 256, 0, stream>>>(p, r2, out1, deg, cursor, adj, W2, out, N);
}

// Round 9
// 420.163 us; speedup vs baseline: 1.5311x; 1.2643x over previous
//
#include <hip/hip_runtime.h>

#define FIN 128
#define FHID 32
#define FOUT 64
#define MAXDEG 10
#define BSH 8              // dst bucket = dst >> 8 (256 dsts per bucket)
#define ACHUNK 4096        // edges per pass-A workgroup (16 per thread)
#define XPAD 136           // LDS row stride (bf16) for 128-k tiles: 272B = 16B-aligned, +4-bank skew
#define YPAD 40            // LDS row stride (bf16) for 32-k tiles: 80B aligned

typedef __attribute__((ext_vector_type(8))) short short8;
typedef __attribute__((ext_vector_type(4))) float f32x4;

// edge_index arrives as int32 (harness converts integer inputs to int):
// layout [2, E] flat: src = ei[e], dst = ei[E + e].

__device__ __forceinline__ float bf2f(unsigned short u) {
    union { unsigned int i; float f; } c; c.i = ((unsigned int)u) << 16; return c.f;
}
__device__ __forceinline__ unsigned short f2bf(float f) {
    union { float f; unsigned int i; } c; c.f = f;
    unsigned int r = c.i + 0x7FFF + ((c.i >> 16) & 1);   // round-nearest-even
    return (unsigned short)(r >> 16);
}
__device__ __forceinline__ float bflo(unsigned int w) { return bf2f((unsigned short)(w & 0xffff)); }
__device__ __forceinline__ float bfhi(unsigned int w) { return bf2f((unsigned short)(w >> 16)); }

// ---------- CSR build ----------

__global__ __launch_bounds__(256) void k_count(const int* __restrict__ ei, int E, int N,
                                               int* __restrict__ deg) {
    int e = blockIdx.x * 256 + threadIdx.x;
    if (e >= E) return;
    int d = ei[E + e];
    if ((unsigned)d < (unsigned)N) atomicAdd(deg + d, 1);
}

__global__ __launch_bounds__(256) void k_blocksum(const int* __restrict__ deg, int N,
                                                  int* __restrict__ partial) {
    __shared__ int tmp[256];
    int t = threadIdx.x;
    int i = blockIdx.x * 256 + t;
    tmp[t] = (i < N) ? deg[i] : 0;
    __syncthreads();
    for (int off = 128; off > 0; off >>= 1) {
        if (t < off) tmp[t] += tmp[t + off];
        __syncthreads();
    }
    if (t == 0) partial[blockIdx.x] = tmp[0];
}

// single-block exclusive scan of partial[0..NB) -> offsets   (requires NB <= 1024)
__global__ __launch_bounds__(1024) void k_scanpartial(const int* __restrict__ partial, int NB,
                                                      int* __restrict__ offsets) {
    __shared__ int tmp[1024];
    int t = threadIdx.x;
    int v = (t < NB) ? partial[t] : 0;
    tmp[t] = v;
    __syncthreads();
    for (int off = 1; off < 1024; off <<= 1) {
        int a = (t >= off) ? tmp[t - off] : 0;
        __syncthreads();
        tmp[t] += a;
        __syncthreads();
    }
    if (t < NB) offsets[t] = tmp[t] - v;
}

__global__ __launch_bounds__(256) void k_scandeg(const int* __restrict__ deg, int N,
                                                 const int* __restrict__ offsets,
                                                 int* __restrict__ cursor) {
    __shared__ int tmp[256];
    int t = threadIdx.x;
    int i = blockIdx.x * 256 + t;
    int v = (i < N) ? deg[i] : 0;
    tmp[t] = v;
    __syncthreads();
    for (int off = 1; off < 256; off <<= 1) {
        int a = (t >= off) ? tmp[t - off] : 0;
        __syncthreads();
        tmp[t] += a;
        __syncthreads();
    }
    if (i < N) cursor[i] = offsets[blockIdx.x] + tmp[t] - v;
}

// gcur[b] = adj start offset of bucket b (= row start of first dst in bucket)
__global__ __launch_bounds__(256) void k_initb(const int* __restrict__ cursor,
                                               int* __restrict__ gcur, int K) {
    int b = blockIdx.x * 256 + threadIdx.x;
    if (b < K) gcur[b] = cursor[b << BSH];
}

// Pass A: bucket edges by dst>>8 into pairs[], line-coalesced appends.
__global__ __launch_bounds__(256) void k_passA(const int* __restrict__ ei, int E, int N,
                                               int* __restrict__ gcur,
                                               int2* __restrict__ pairs) {
    __shared__ int hist[1024];
    __shared__ int base[1024];
    int K = ((N + 255) >> BSH);
    int t = threadIdx.x;
    long long cb = (long long)blockIdx.x * ACHUNK;
    for (int i = t; i < K; i += 256) hist[i] = 0;
    __syncthreads();
    int sv[16], dv[16];
#pragma unroll
    for (int i = 0; i < 16; ++i) {
        sv[i] = -1; dv[i] = 0;
        long long e = cb + t + (long long)i * 256;
        if (e < E) {
            int ss = ei[e];
            int dd = ei[E + e];
            if ((unsigned)ss < (unsigned)N && (unsigned)dd < (unsigned)N) {
                sv[i] = ss; dv[i] = dd;
            }
        }
    }
#pragma unroll
    for (int i = 0; i < 16; ++i)
        if (sv[i] >= 0) atomicAdd(&hist[dv[i] >> BSH], 1);
    __syncthreads();
    for (int i = t; i < K; i += 256) {
        int h = hist[i];
        base[i] = h ? atomicAdd(&gcur[i], h) : 0;
    }
    __syncthreads();
    for (int i = t; i < K; i += 256) hist[i] = 0;
    __syncthreads();
#pragma unroll
    for (int i = 0; i < 16; ++i) {
        if (sv[i] >= 0) {
            int b = dv[i] >> BSH;
            int off = atomicAdd(&hist[b], 1);
            pairs[base[b] + off] = make_int2(sv[i], dv[i]);
        }
    }
}

// Pass B: one workgroup per bucket; private LDS cursors; flushes row ends.
__global__ __launch_bounds__(256) void k_passB(const int2* __restrict__ pairs,
                                               const int* __restrict__ gcur,
                                               int* __restrict__ cursor,
                                               int* __restrict__ adj, int N) {
    __shared__ int cur[256];
    int b = blockIdx.x;
    int lo = b << BSH;
    int hi = min(lo + 256, N);
    int t = threadIdx.x;
    int cnt = hi - lo;
    if (t < cnt) cur[t] = cursor[lo + t];
    int pstart = cursor[lo];
    int pend = gcur[b];
    __syncthreads();
    for (int i = pstart + t; i < pend; i += 256) {
        int2 pr = pairs[i];
        int pos = atomicAdd(&cur[pr.y - lo], 1);
        adj[pos] = pr.x;
    }
    __syncthreads();
    if (t < cnt) cursor[lo + t] = cur[t];
}

// ---------- prepack bucket-10 weights as bf16, B-operand layout [n][k] ----------
__global__ __launch_bounds__(256) void k_prepack(const float* __restrict__ W1,
                                                 const float* __restrict__ Wr1,
                                                 const float* __restrict__ W2,
                                                 const float* __restrict__ Wr2,
                                                 unsigned short* __restrict__ wcat1,
                                                 unsigned short* __restrict__ wcat2) {
    int t = threadIdx.x;
    const float* W1b  = W1  + (size_t)MAXDEG * FIN * FHID;
    const float* Wr1b = Wr1 + (size_t)MAXDEG * FIN * FHID;
    const float* W2b  = W2  + (size_t)MAXDEG * FHID * FOUT;
    const float* Wr2b = Wr2 + (size_t)MAXDEG * FHID * FOUT;
    // wcat1: [64 n][128 k]; n<32 -> W1[10][k][n], else Wr1[10][k][n-32]
    for (int i = 0; i < 32; ++i) {
        int idx = i * 256 + t;            // 8192
        int n = idx >> 7, k = idx & 127;
        float v = (n < 32) ? W1b[k * FHID + n] : Wr1b[k * FHID + (n - 32)];
        wcat1[idx] = f2bf(v);
    }
    // wcat2: [128 n][32 k]; n<64 -> W2[10][k][n], else Wr2[10][k][n-64]
    for (int i = 0; i < 16; ++i) {
        int idx = i * 256 + t;            // 4096
        int n = idx >> 5, k = idx & 31;
        float v = (n < 64) ? W2b[k * FOUT + n] : Wr2b[k * FOUT + (n - 64)];
        wcat2[idx] = f2bf(v);
    }
}

// ---------- pre1 (MFMA): [z10 | r1] = x @ [W1[10] | Wr1[10]] + [0 | b1[10]] ----------
// 64 nodes per block; wave w does rows w*16..+16 x all 64 cols = 16 MFMAs.
// A: xt[m=lane&15][quad*8+j]; B: wt[n=lane&15][quad*8+j]; C: col=lane&15,row=quad*4+reg.
__global__ __launch_bounds__(256) void k_pre1m(const float* __restrict__ x,
                                               const unsigned short* __restrict__ wcat1,
                                               const float* __restrict__ b1,
                                               unsigned short* __restrict__ z10,
                                               unsigned short* __restrict__ r1, int N) {
    __shared__ __align__(16) unsigned short xt[64 * XPAD];
    __shared__ __align__(16) unsigned short wt[64 * XPAD];
    int t = threadIdx.x;
    int row0 = blockIdx.x * 64;
    {   // stage Wcat1 (8192 bf16 = 1024 uint4)
        const uint4* src = (const uint4*)wcat1;
#pragma unroll
        for (int i = 0; i < 4; ++i) {
            int idx = i * 256 + t;
            uint4 v = src[idx];
            int n = idx >> 4;
            int k = (idx & 15) * 8;
            *(uint4*)(wt + n * XPAD + k) = v;
        }
    }
    {   // stage x rows -> bf16
        int r = t >> 2;
        int c0 = (t & 3) * 32;
        int cr = min(row0 + r, N - 1);
        const float4* xs = (const float4*)(x + (size_t)cr * FIN + c0);
        unsigned short* dst = xt + r * XPAD + c0;
#pragma unroll
        for (int i = 0; i < 8; ++i) {
            float4 v = xs[i];
            ushort4 b;
            b.x = f2bf(v.x); b.y = f2bf(v.y); b.z = f2bf(v.z); b.w = f2bf(v.w);
            *(ushort4*)(dst + i * 4) = b;
        }
    }
    __syncthreads();
    int w = t >> 6, lane = t & 63;
    int m = lane & 15, quad = lane >> 4;
    const unsigned short* arow = xt + (w * 16 + m) * XPAD + quad * 8;
    short8 af[4];
#pragma unroll
    for (int kt = 0; kt < 4; ++kt) af[kt] = *(const short8*)(arow + kt * 32);
    f32x4 acc[4];
#pragma unroll
    for (int ct = 0; ct < 4; ++ct) acc[ct] = (f32x4){0.f, 0.f, 0.f, 0.f};
#pragma unroll
    for (int ct = 0; ct < 4; ++ct) {
        const unsigned short* brow = wt + (ct * 16 + m) * XPAD + quad * 8;
#pragma unroll
        for (int kt = 0; kt < 4; ++kt) {
            short8 bfr = *(const short8*)(brow + kt * 32);
            acc[ct] = __builtin_amdgcn_mfma_f32_16x16x32_bf16(af[kt], bfr, acc[ct], 0, 0, 0);
        }
    }
    int rbase = row0 + w * 16 + quad * 4;
#pragma unroll
    for (int ct = 0; ct < 4; ++ct) {
        float bias = (ct >= 2) ? b1[MAXDEG * FHID + (ct - 2) * 16 + m] : 0.f;
#pragma unroll
        for (int rg = 0; rg < 4; ++rg) {
            int n = rbase + rg;
            if (n < N) {
                float v = acc[ct][rg];
                if (ct < 2) z10[(size_t)n * FHID + ct * 16 + m] = f2bf(v);
                else        r1[(size_t)n * FHID + (ct - 2) * 16 + m] = f2bf(v + bias);
            }
        }
    }
}

// ---------- pre2 (MFMA): [p | r2] = y @ [W2[10] | Wr2[10]] + [0 | b2[10]] ----------
__global__ __launch_bounds__(256) void k_pre2m(const unsigned short* __restrict__ y,
                                               const unsigned short* __restrict__ wcat2,
                                               const float* __restrict__ b2,
                                               unsigned short* __restrict__ p,
                                               unsigned short* __restrict__ r2, int N) {
    __shared__ __align__(16) unsigned short yt[64 * YPAD];
    __shared__ __align__(16) unsigned short wt[128 * YPAD];
    int t = threadIdx.x;
    int row0 = blockIdx.x * 64;
    {   // stage wcat2 (4096 bf16 = 512 uint4)
        const uint4* src = (const uint4*)wcat2;
#pragma unroll
        for (int i = 0; i < 2; ++i) {
            int idx = i * 256 + t;
            uint4 v = src[idx];
            int n = idx >> 2;
            int k = (idx & 3) * 8;
            *(uint4*)(wt + n * YPAD + k) = v;
        }
    }
    {   // stage y rows (already bf16)
        int r = t >> 2, c0 = (t & 3) * 8;
        int cr = min(row0 + r, N - 1);
        uint4 v = *(const uint4*)(y + (size_t)cr * FHID + c0);
        *(uint4*)(yt + r * YPAD + c0) = v;
    }
    __syncthreads();
    int w = t >> 6, lane = t & 63;
    int m = lane & 15, quad = lane >> 4;
    short8 af = *(const short8*)(yt + (w * 16 + m) * YPAD + quad * 8);
    int rbase = row0 + w * 16 + quad * 4;
#pragma unroll
    for (int ct = 0; ct < 8; ++ct) {
        short8 bfr = *(const short8*)(wt + (ct * 16 + m) * YPAD + quad * 8);
        f32x4 acc = (f32x4){0.f, 0.f, 0.f, 0.f};
        acc = __builtin_amdgcn_mfma_f32_16x16x32_bf16(af, bfr, acc, 0, 0, 0);
        float bias = (ct >= 4) ? b2[MAXDEG * FOUT + (ct - 4) * 16 + m] : 0.f;
#pragma unroll
        for (int rg = 0; rg < 4; ++rg) {
            int n = rbase + rg;
            if (n < N) {
                float v = acc[rg];
                if (ct < 4) p[(size_t)n * FOUT + ct * 16 + m] = f2bf(v);
                else        r2[(size_t)n * FOUT + (ct - 4) * 16 + m] = f2bf(v + bias);
            }
        }
    }
}

// fixup: recompute r1 with the node's true bucket for the ~4% deg<10 nodes.
__global__ __launch_bounds__(256) void k_fix1(const float* __restrict__ x,
                                              const int* __restrict__ deg,
                                              const float* __restrict__ b1,
                                              const float* __restrict__ Wr1,
                                              unsigned short* __restrict__ r1, int N) {
    int wavebase = blockIdx.x * 256 + (threadIdx.x & 192);
    int lane = threadIdx.x & 63;
    int nl = wavebase + lane;
    bool fl = (nl < N) && (deg[nl] < MAXDEG);
    unsigned long long mask = __ballot(fl);
    int u = lane >> 5, o = lane & 31;
    while (mask) {
        int b = __ffsll(mask) - 1;
        mask &= mask - 1;
        int n = wavebase + b;
        int d = deg[n];
        const float* Wr = Wr1 + (size_t)d * (FIN * FHID) + o;
        const float4* xr = (const float4*)(x + (size_t)n * FIN);
        float acc = 0.f;
        for (int c = u * 16; c < u * 16 + 16; ++c) {   // split-K across halves
            float4 xv = xr[c];
            acc += xv.x * Wr[(c * 4 + 0) * FHID] + xv.y * Wr[(c * 4 + 1) * FHID]
                 + xv.z * Wr[(c * 4 + 2) * FHID] + xv.w * Wr[(c * 4 + 3) * FHID];
        }
        acc += __shfl_xor(acc, 32);
        if (lane < 32) r1[(size_t)n * FHID + o] = f2bf(acc + b1[d * FHID + o]);
    }
}

// ---------- layer1: deg>=10 fast path gathers bf16 z10 rows with high MLP ----------
__global__ __launch_bounds__(256) void k_layer1b(const float* __restrict__ x,
                                                 const unsigned short* __restrict__ z10,
                                                 const unsigned short* __restrict__ r1,
                                                 const int* __restrict__ deg,
                                                 const int* __restrict__ cursor,
                                                 const int* __restrict__ adj,
                                                 const float* __restrict__ W1,
                                                 unsigned short* __restrict__ out1, int N) {
    int wave = (int)(((long long)blockIdx.x * 256 + threadIdx.x) >> 6);
    if (wave >= N) return;
    int n = wave;
    int lane = threadIdx.x & 63;
    int dg = deg[n];
    int e1 = cursor[n];
    int e0 = e1 - dg;
    if (dg >= MAXDEG) {
        int g = lane >> 3, l = lane & 7;
        int myk = e0 + lane;
        int sidx = (myk < e1) ? adj[myk] : 0;
        int cnt = min(dg, 64);
        float a0 = 0.f, a1 = 0.f, a2 = 0.f, a3 = 0.f;
        for (int i = 0; i * 8 < cnt; ++i) {
            int idx = i * 8 + g;
            int s = __shfl(sidx, idx);
            if (idx < cnt) {
                ushort4 uv = *(const ushort4*)(z10 + (size_t)s * FHID + l * 4);
                a0 += bf2f(uv.x); a1 += bf2f(uv.y); a2 += bf2f(uv.z); a3 += bf2f(uv.w);
            }
        }
        for (int k = e0 + 64 + g; k < e1; k += 8) {
            int s = adj[k];
            ushort4 uv = *(const ushort4*)(z10 + (size_t)s * FHID + l * 4);
            a0 += bf2f(uv.x); a1 += bf2f(uv.y); a2 += bf2f(uv.z); a3 += bf2f(uv.w);
        }
#pragma unroll
        for (int m = 8; m <= 32; m <<= 1) {
            a0 += __shfl_xor(a0, m); a1 += __shfl_xor(a1, m);
            a2 += __shfl_xor(a2, m); a3 += __shfl_xor(a3, m);
        }
        if (lane < 8) {
            ushort4 rv = *(const ushort4*)(r1 + (size_t)n * FHID + l * 4);
            ushort4 w;
            w.x = f2bf(fmaxf(a0 + bf2f(rv.x), 0.f));
            w.y = f2bf(fmaxf(a1 + bf2f(rv.y), 0.f));
            w.z = f2bf(fmaxf(a2 + bf2f(rv.z), 0.f));
            w.w = f2bf(fmaxf(a3 + bf2f(rv.w), 0.f));
            *(ushort4*)(out1 + (size_t)n * FHID + l * 4) = w;
        }
    } else {
        float2 hs = make_float2(0.f, 0.f);
        for (int k = e0; k < e1; ++k) {
            int s = adj[k];
            float2 v = *(const float2*)(x + (size_t)s * FIN + lane * 2);
            hs.x += v.x; hs.y += v.y;
        }
        int o = lane & 31;
        const float* Wp = W1 + (size_t)dg * (FIN * FHID) + o;
        float acc = 0.f;
#pragma unroll
        for (int f = 0; f < FIN; ++f) {
            float hv = __shfl((f & 1) ? hs.y : hs.x, f >> 1);
            acc += hv * Wp[f * FHID];
        }
        if (lane < 32) {
            float rv = bf2f(r1[(size_t)n * FHID + o]);
            out1[(size_t)n * FHID + o] = f2bf(fmaxf(acc + rv, 0.f));
        }
    }
}

// fixup: recompute r2 with the node's true bucket for deg<10 nodes.
__global__ __launch_bounds__(256) void k_fix2(const unsigned short* __restrict__ y,
                                              const int* __restrict__ deg,
                                              const float* __restrict__ b2,
                                              const float* __restrict__ Wr2,
                                              unsigned short* __restrict__ r2, int N) {
    int wavebase = blockIdx.x * 256 + (threadIdx.x & 192);
    int lane = threadIdx.x & 63;
    int nl = wavebase + lane;
    bool fl = (nl < N) && (deg[nl] < MAXDEG);
    unsigned long long mask = __ballot(fl);
    while (mask) {
        int b = __ffsll(mask) - 1;
        mask &= mask - 1;
        int n = wavebase + b;
        int d = deg[n];
        const float* Wr = Wr2 + (size_t)d * (FHID * FOUT) + lane;
        const uint4* yr = (const uint4*)(y + (size_t)n * FHID);
        float acc = b2[d * FOUT + lane];
        for (int c = 0; c < 4; ++c) {
            uint4 yv = yr[c];
            acc += bflo(yv.x) * Wr[(c * 8 + 0) * FOUT] + bfhi(yv.x) * Wr[(c * 8 + 1) * FOUT]
                 + bflo(yv.y) * Wr[(c * 8 + 2) * FOUT] + bfhi(yv.y) * Wr[(c * 8 + 3) * FOUT]
                 + bflo(yv.z) * Wr[(c * 8 + 4) * FOUT] + bfhi(yv.z) * Wr[(c * 8 + 5) * FOUT]
                 + bflo(yv.w) * Wr[(c * 8 + 6) * FOUT] + bfhi(yv.w) * Wr[(c * 8 + 7) * FOUT];
        }
        r2[(size_t)n * FOUT + lane] = f2bf(acc);
    }
}

// ---------- layer2: deg>=10 fast path gathers bf16 p rows (128B) with high MLP ----------
__global__ __launch_bounds__(256) void k_layer2b(const unsigned short* __restrict__ p,
                                                 const unsigned short* __restrict__ r2,
                                                 const unsigned short* __restrict__ y,
                                                 const int* __restrict__ deg,
                                                 const int* __restrict__ cursor,
                                                 const int* __restrict__ adj,
                                                 const float* __restrict__ W2,
                                                 float* __restrict__ out, int N) {
    int wave = (int)(((long long)blockIdx.x * 256 + threadIdx.x) >> 6);
    if (wave >= N) return;
    int n = wave;
    int lane = threadIdx.x & 63;
    int dg = deg[n];
    int e1 = cursor[n];
    int e0 = e1 - dg;
    if (dg >= MAXDEG) {
        int g = lane >> 3, l = lane & 7;
        int myk = e0 + lane;
        int sidx = (myk < e1) ? adj[myk] : 0;
        int cnt = min(dg, 64);
        float a[8];
#pragma unroll
        for (int m = 0; m < 8; ++m) a[m] = 0.f;
        for (int i = 0; i * 8 < cnt; ++i) {
            int idx = i * 8 + g;
            int s = __shfl(sidx, idx);
            if (idx < cnt) {
                uint4 uv = *(const uint4*)(p + (size_t)s * FOUT + l * 8);
                a[0] += bflo(uv.x); a[1] += bfhi(uv.x);
                a[2] += bflo(uv.y); a[3] += bfhi(uv.y);
                a[4] += bflo(uv.z); a[5] += bfhi(uv.z);
                a[6] += bflo(uv.w); a[7] += bfhi(uv.w);
            }
        }
        for (int k = e0 + 64 + g; k < e1; k += 8) {
            int s = adj[k];
            uint4 uv = *(const uint4*)(p + (size_t)s * FOUT + l * 8);
            a[0] += bflo(uv.x); a[1] += bfhi(uv.x);
            a[2] += bflo(uv.y); a[3] += bfhi(uv.y);
            a[4] += bflo(uv.z); a[5] += bfhi(uv.z);
            a[6] += bflo(uv.w); a[7] += bfhi(uv.w);
        }
#pragma unroll
        for (int m = 8; m <= 32; m <<= 1) {
#pragma unroll
            for (int t = 0; t < 8; ++t) a[t] += __shfl_xor(a[t], m);
        }
        if (lane < 8) {
            uint4 rv = *(const uint4*)(r2 + (size_t)n * FOUT + l * 8);
            float4 o0, o1;
            o0.x = a[0] + bflo(rv.x); o0.y = a[1] + bfhi(rv.x);
            o0.z = a[2] + bflo(rv.y); o0.w = a[3] + bfhi(rv.y);
            o1.x = a[4] + bflo(rv.z); o1.y = a[5] + bfhi(rv.z);
            o1.z = a[6] + bflo(rv.w); o1.w = a[7] + bfhi(rv.w);
            float* op = out + (size_t)n * FOUT + l * 8;
            *(float4*)op = o0;
            *(float4*)(op + 4) = o1;
        }
    } else {
        int g = lane >> 4, l = lane & 15;
        float2 h = make_float2(0.f, 0.f);
        for (int k = e0 + g; k < e1; k += 4) {
            int s = adj[k];
            ushort2 uv = *(const ushort2*)(y + (size_t)s * FHID + l * 2);
            h.x += bf2f(uv.x); h.y += bf2f(uv.y);
        }
        h.x += __shfl_xor(h.x, 16); h.y += __shfl_xor(h.y, 16);
        h.x += __shfl_xor(h.x, 32); h.y += __shfl_xor(h.y, 32);
        const float* Wp = W2 + (size_t)dg * (FHID * FOUT) + lane;
        float acc = bf2f(r2[(size_t)n * FOUT + lane]);
#pragma unroll
        for (int f = 0; f < FHID; ++f) {
            float hf = __shfl((f & 1) ? h.y : h.x, f >> 1);
            acc += hf * Wp[f * FOUT];
        }
        out[(size_t)n * FOUT + lane] = acc;
    }
}

extern "C" void kernel_launch(void* const* d_in, const int* in_sizes, int n_in,
                              void* d_out, int out_size, void* d_ws, size_t ws_size,
                              hipStream_t stream) {
    const float* x   = (const float*)d_in[0];
    const int*   ei  = (const int*)d_in[1];   // int32, [2, E] flat
    const float* W1  = (const float*)d_in[2];
    const float* b1  = (const float*)d_in[3];
    const float* Wr1 = (const float*)d_in[4];
    const float* W2  = (const float*)d_in[5];
    const float* b2  = (const float*)d_in[6];
    const float* Wr2 = (const float*)d_in[7];

    int N = in_sizes[0] / FIN;
    int E = in_sizes[1] / 2;
    int NB = (N + 255) / 256;
    int K  = (N + 255) >> BSH;   // dst buckets

    char* ws = (char*)d_ws;
    size_t off = 0;
    auto alloc = [&](size_t bytes) {
        void* ptr = ws + off;
        off += (bytes + 511) / 512 * 512;
        return ptr;
    };
    int* deg              = (int*)alloc((size_t)N * sizeof(int));
    int* cursor           = (int*)alloc((size_t)N * sizeof(int));
    int* partial          = (int*)alloc((size_t)NB * sizeof(int));
    int* offsets          = (int*)alloc((size_t)NB * sizeof(int));
    int* gcur             = (int*)alloc((size_t)K * sizeof(int));
    int* adj              = (int*)alloc((size_t)E * sizeof(int));
    unsigned short* z10   = (unsigned short*)alloc((size_t)N * FHID * 2);
    unsigned short* r1    = (unsigned short*)alloc((size_t)N * FHID * 2);
    unsigned short* out1  = (unsigned short*)alloc((size_t)N * FHID * 2);
    unsigned short* p     = (unsigned short*)alloc((size_t)N * FOUT * 2);
    unsigned short* r2    = (unsigned short*)alloc((size_t)N * FOUT * 2);
    unsigned short* wcat1 = (unsigned short*)alloc(64 * 128 * 2);
    unsigned short* wcat2 = (unsigned short*)alloc(128 * 32 * 2);
    // pairs (E*8B = 12.8MB) aliases p (N*FOUT*2 = 12.8MB): dead until k_pre2m runs.
    int2* pairs = (int2*)p;

    float* out = (float*)d_out;

    hipMemsetAsync(deg, 0, (size_t)N * sizeof(int), stream);

    int eb = (E + 255) / 256;
    k_prepack<<<1, 256, 0, stream>>>(W1, Wr1, W2, Wr2, wcat1, wcat2);
    k_count<<<eb, 256, 0, stream>>>(ei, E, N, deg);
    k_blocksum<<<NB, 256, 0, stream>>>(deg, N, partial);
    k_scanpartial<<<1, 1024, 0, stream>>>(partial, NB, offsets);
    k_scandeg<<<NB, 256, 0, stream>>>(deg, N, offsets, cursor);
    k_initb<<<(K + 255) / 256, 256, 0, stream>>>(cursor, gcur, K);
    int nwgA = (E + ACHUNK - 1) / ACHUNK;
    k_passA<<<nwgA, 256, 0, stream>>>(ei, E, N, gcur, pairs);
    k_passB<<<K, 256, 0, stream>>>(pairs, gcur, cursor, adj, N);

    int nb64 = (N + 63) / 64;     // MFMA pre kernels: 64 nodes per block
    int nbfx = (N + 255) / 256;   // fixups: wave scans 64 nodes
    int nb_node = (N + 3) / 4;    // layer kernels: wave per node

    k_pre1m<<<nb64, 256, 0, stream>>>(x, wcat1, b1, z10, r1, N);
    k_fix1<<<nbfx, 256, 0, stream>>>(x, deg, b1, Wr1, r1, N);
    k_layer1b<<<nb_node, 256, 0, stream>>>(x, z10, r1, deg, cursor, adj, W1, out1, N);
    k_pre2m<<<nb64, 256, 0, stream>>>(out1, wcat2, b2, p, r2, N);
    k_fix2<<<nbfx, 256, 0, stream>>>(out1, deg, b2, Wr2, r2, N);
    k_layer2b<<<nb_node, 256, 0, stream>>>(p, r2, out1, deg, cursor, adj, W2, out, N);
}